// Round 2
// baseline (9751.220 us; speedup 1.0000x reference)
//
#include <hip/hip_runtime.h>
#include <hip/hip_fp16.h>
#include <cmath>

typedef _Float16 f16;
typedef _Float16 half8 __attribute__((ext_vector_type(8)));
typedef float f32x4 __attribute__((ext_vector_type(4)));

#define P_WG   75          // workgroups (one per p; each handles BOTH directions)
#define GRID_MAIN P_WG
#define G      12          // XZ lookahead distance
#define RING   13          // XZ ring slots (G+1)

#define X16_ELEMS  (64u*512u*320u)            // 10,485,760 f16 per plane
#define BPK_HALF   (2u*75u*2u*30u*64u*8u)     // 4,608,000 f16 (one term plane)
#define HBUF_F16   (2u*2u*64u*640u)           // dirs*bufs*rows*cols f16
#define HBUF_WORDS (HBUF_F16/2u)              // 81,920 u32
#define FLAG_WORDS 256u                       // 2 dirs x 128 u32 (75 flags + pads)
#define E_OFF      96u                        // (legacy epoch slot, unused now)

// ---------------- prep: rebuild all workspace state every launch ----------------
__global__ void lstm_prep(const float* __restrict__ x,
                          const float* __restrict__ Wf, const float* __restrict__ Uf,
                          const float* __restrict__ Wb, const float* __restrict__ Ub,
                          const int* __restrict__ len,
                          f16* __restrict__ x16h, f16* __restrict__ x16l,
                          f16* __restrict__ Bpk,
                          unsigned* __restrict__ hbw, unsigned* __restrict__ flags,
                          int* __restrict__ maxT, float* __restrict__ outp)
{
    const unsigned total = X16_ELEMS + BPK_HALF + HBUF_WORDS + FLAG_WORDS + 2u;
    for (unsigned e = blockIdx.x * blockDim.x + threadIdx.x; e < total;
         e += gridDim.x * blockDim.x) {
        if (e < X16_ELEMS) {
            unsigned k = e % 320u, r = e / 320u;   // r = b*512 + t
            float v = (k < 300u) ? x[r * 300u + k] : 0.0f;
            f16 hi = (f16)v;
            x16h[e] = hi;
            x16l[e] = (f16)((v - (float)hi) * 2048.0f);
        } else if (e < X16_ELEMS + BPK_HALF) {
            unsigned i = e - X16_ELEMS;
            // layout: [dir][p][term][nt][kt][lane][8]
            unsigned j    = i & 7u,  r1 = i >> 3;
            unsigned lane = r1 & 63u, r2 = r1 >> 6;
            unsigned kt   = r2 % 30u, r3 = r2 / 30u;
            unsigned nt   = r3 & 1u,  r4 = r3 >> 1;
            unsigned p    = r4 % 75u, dw = r4 / 75u;
            unsigned k = kt * 32u + (lane >> 4) * 8u + j;     // B[k][n], k-octet per quad
            unsigned n = nt * 16u + (lane & 15u);             // n = gate*8 + jj
            unsigned c = (n >> 3) * 600u + p * 8u + (n & 7u); // source column in [0,2400)
            float v = 0.0f;
            if (k < 300u)                    v = (dw ? Wb : Wf)[k * 2400u + c];
            else if (k >= 320u && k < 920u)  v = (dw ? Ub : Uf)[(k - 320u) * 2400u + c];
            f16 hi = (f16)v;
            unsigned base = (((((dw * 75u + p) * 2u + 0u) * 2u + nt) * 30u + kt) * 64u + lane) * 8u + j;
            Bpk[base]          = hi;
            Bpk[base + 30720u] = (f16)((v - (float)hi) * 2048.0f); // lo pre-scaled by 2^11
        } else if (e < X16_ELEMS + BPK_HALF + HBUF_WORDS) {
            hbw[e - X16_ELEMS - BPK_HALF] = 0u;   // zero h ping-pong buffers, both dirs
        } else if (e < X16_ELEMS + BPK_HALF + HBUF_WORDS + FLAG_WORDS) {
            unsigned q = e - (X16_ELEMS + BPK_HALF + HBUF_WORDS);
            unsigned q7 = q & 127u;
            flags[q] = (q7 < 75u) ? 0u : 0xFFFFFFFFu;   // pads always satisfied
        } else {
            unsigned q = e - (X16_ELEMS + BPK_HALF + HBUF_WORDS + FLAG_WORDS);
            if (q == 0u) {
                int m = 1;
                for (int b = 0; b < 64; ++b) { int L = len[b]; m = (L > m) ? L : m; }
                *maxT = m;
            } else {
                outp[0] = 1000.0f;   // sentinel: lstm_main always overwrites out[0]
            }
        }
    }
}

// ---------------- main persistent recurrent kernel ----------------
__global__ __launch_bounds__(256, 1)
void lstm_main(const f16* __restrict__ x16h, const f16* __restrict__ x16l,
               const f16* __restrict__ Bpk,
               f16* __restrict__ hbuf, float* __restrict__ xz,
               unsigned* flags, const int* __restrict__ maxT,
               const int* __restrict__ len,
               const float* __restrict__ bfv, const float* __restrict__ bbv,
               float* __restrict__ out)
{
    __shared__ f32x4 obox[4][4][2][64];   // 32 KB merge buffer (reused by both dirs)
    __shared__ f16 hstage[64][8];         // h transpose staging: 1 KB
    __shared__ f16 Blds[2][4][10][512];   // xz-part B, both dirs: 80 KB

    const int tid  = threadIdx.x;
    const int wave = tid >> 6, lane = tid & 63;
    const int quad = lane >> 4, l15 = lane & 15;
    const int p    = blockIdx.x;
    const int pc   = p * 8;

    const int s0 = (wave < 2) ? 3 : 2;    // kt = wave + 4*(s0+sp), sp=0..4

    // per-dir uniform state
    const unsigned bb_base[2] = { (unsigned)(0 * 75 + p) * 4u * 30u * 512u,
                                  (unsigned)(1 * 75 + p) * 4u * 30u * 512u };
    f16* hb[2]      = { hbuf, hbuf + (2 * 64 * 640) };
    unsigned* fl[2] = { flags, flags + 128 };
    float* mx[2]    = { xz + (size_t)(p * 2 + 0) * (RING * 64 * 32),
                        xz + (size_t)(p * 2 + 1) * (RING * 64 * 32) };
    float b0a[2], b1a[2];
    {
        const int c0 = ((l15 >> 3)) * 600 + pc + (l15 & 7);
        const int c1 = ((l15 >> 3) + 2) * 600 + pc + (l15 & 7);
        b0a[0] = bfv[c0]; b1a[0] = bfv[c1];
        b0a[1] = bbv[c0]; b1a[1] = bbv[c1];
    }

    int Lm[4], Lr[4];
#pragma unroll
    for (int mt = 0; mt < 4; ++mt) Lm[mt] = len[mt * 16 + l15];        // initial-burst A rows
    const int Lw = len[wave * 16 + l15];                               // steady-burst A rows
#pragma unroll
    for (int r = 0; r < 4; ++r)   Lr[r]  = len[wave * 16 + quad * 4 + r]; // epilogue rows

    float cst[2][4] = {{0,0,0,0},{0,0,0,0}}, sum[2][4] = {{0,0,0,0},{0,0,0,0}};
    const int T = *maxT;

    // ---- stage the xz-part B tiles (kt 0..9, 4 tm/nt blocks) for BOTH dirs into LDS ----
#pragma unroll
    for (int dd = 0; dd < 2; ++dd) {
        f16* bl = &Blds[dd][0][0][0];
#pragma unroll
        for (int blk = 0; blk < 4; ++blk)
            for (int i = tid; i < 640; i += 256)
                *(half8*)(bl + blk * 5120 + i * 8) =
                    *(const half8*)(Bpk + bb_base[dd] + (unsigned)blk * 15360u + (unsigned)i * 8u);
    }
    __syncthreads();

    // ---- initial burst: fill XZ ring slots 0..G-1 for both dirs ----
#pragma unroll
    for (int dd = 0; dd < 2; ++dd) {
#pragma unroll
        for (int jc = 0; jc < 3; ++jc) {
            int g = wave * 3 + jc;
            int tt = (g < 512) ? g : 511;
            unsigned arow[4];
#pragma unroll
            for (int mt = 0; mt < 4; ++mt) {
                int tx = tt;
                if (dd) tx = (tt < Lm[mt]) ? (Lm[mt] - 1 - tt) : tt;  // reverse_sequence
                arow[mt] = ((unsigned)(mt * 16 + l15) * 512u + (unsigned)tx) * 320u + quad * 8;
            }
            f32x4 aH[4][2], aM[4][2];
#pragma unroll
            for (int mt = 0; mt < 4; ++mt)
#pragma unroll
                for (int nt = 0; nt < 2; ++nt) {
                    aH[mt][nt] = f32x4{0.f, 0.f, 0.f, 0.f};
                    aM[mt][nt] = f32x4{0.f, 0.f, 0.f, 0.f};
                }
#pragma unroll
            for (int kt = 0; kt < 10; ++kt) {
                const f16* bb = &Blds[dd][0][0][0] + kt * 512 + lane * 8;
                half8 B00 = *(const half8*)(bb);
                half8 B01 = *(const half8*)(bb + 5120);
                half8 B10 = *(const half8*)(bb + 10240);
                half8 B11 = *(const half8*)(bb + 15360);
#pragma unroll
                for (int mt = 0; mt < 4; ++mt) {
                    half8 Ah = *(const half8*)(x16h + arow[mt] + kt * 32);
                    half8 Al = *(const half8*)(x16l + arow[mt] + kt * 32);
                    aH[mt][0] = __builtin_amdgcn_mfma_f32_16x16x32_f16(Ah, B00, aH[mt][0], 0, 0, 0);
                    aM[mt][0] = __builtin_amdgcn_mfma_f32_16x16x32_f16(Ah, B10, aM[mt][0], 0, 0, 0);
                    aM[mt][0] = __builtin_amdgcn_mfma_f32_16x16x32_f16(Al, B00, aM[mt][0], 0, 0, 0);
                    aH[mt][1] = __builtin_amdgcn_mfma_f32_16x16x32_f16(Ah, B01, aH[mt][1], 0, 0, 0);
                    aM[mt][1] = __builtin_amdgcn_mfma_f32_16x16x32_f16(Ah, B11, aM[mt][1], 0, 0, 0);
                    aM[mt][1] = __builtin_amdgcn_mfma_f32_16x16x32_f16(Al, B01, aM[mt][1], 0, 0, 0);
                }
            }
#pragma unroll
            for (int mt = 0; mt < 4; ++mt)
#pragma unroll
                for (int r = 0; r < 4; ++r) {
                    unsigned rowi = (unsigned)(g * 64 + mt * 16 + quad * 4 + r) * 32u;
                    mx[dd][rowi + l15]      = aH[mt][0][r] + aM[mt][0][r] * (1.0f / 2048.0f) + b0a[dd];
                    mx[dd][rowi + 16 + l15] = aH[mt][1][r] + aM[mt][1][r] * (1.0f / 2048.0f) + b1a[dd];
                }
        }
    }
    __syncthreads();   // XZ slots 0..11 visible WG-wide (same CU: L1-coherent)

    for (int t = 0; t < T; ++t) {
#pragma unroll
        for (int dd = 0; dd < 2; ++dd) {
            // ---- issue this dir's resident-B reload (L2-hot; completes during the wait) ----
            half8 Bh[5][2][2];
#pragma unroll
            for (int sp = 0; sp < 5; ++sp) {
                int kt = wave + 4 * (s0 + sp);
#pragma unroll
                for (int nt = 0; nt < 2; ++nt)
#pragma unroll
                    for (int tm = 0; tm < 2; ++tm)
                        Bh[sp][nt][tm] = *(const half8*)(Bpk + bb_base[dd] +
                            ((unsigned)(tm * 2 + nt) * 30u + (unsigned)kt) * 512u + lane * 8);
            }

            // ---- preload this step's XZ into registers (WG-local, L1-warm) ----
            float z0p[4], z1p[4];
            {
                int slot = t % RING;
                unsigned rbase = (unsigned)(slot * 64 + wave * 16 + quad * 4) * 32u;
#pragma unroll
                for (int r = 0; r < 4; ++r) {
                    z0p[r] = mx[dd][rbase + r * 32 + l15];
                    z1p[r] = mx[dd][rbase + r * 32 + 16 + l15];
                }
            }

            const f16* hcur = hb[dd] + (t & 1) * (64 * 640);
            f16*       hnxt = hb[dd] + ((t + 1) & 1) * (64 * 640);
            unsigned*  myflags = fl[dd];

            // ---- wait: wave 0 polls all 75 producer flags for this dir ----
            if (t > 0) {
                const unsigned tgt = (unsigned)t;
                if (wave == 0) {
                    const unsigned long long* f8 = (const unsigned long long*)myflags;
                    for (;;) {
                        unsigned long long v = ~0ull;
                        if (lane < 38)
                            v = __hip_atomic_load(&f8[lane], __ATOMIC_RELAXED, __HIP_MEMORY_SCOPE_AGENT);
                        bool bad = ((unsigned)v < tgt) || ((unsigned)(v >> 32) < tgt);
                        if (!__any(bad)) break;
                        __builtin_amdgcn_s_sleep(1);
                    }
                }
                __syncthreads();
            }

            // ---- h-part: batch-issue MALL loads (rolling 3-deep window), then MFMAs ----
            f32x4 accH[4][2], accM[4][2];
#pragma unroll
            for (int mt = 0; mt < 4; ++mt)
#pragma unroll
                for (int nt = 0; nt < 2; ++nt) {
                    accH[mt][nt] = f32x4{0.f, 0.f, 0.f, 0.f};
                    accM[mt][nt] = f32x4{0.f, 0.f, 0.f, 0.f};
                }

            unsigned long long pre[3][8];     // [window][mt*2+half] : 48 VGPRs
            const f16* hq = hcur + quad * 8;
#define HLOAD(W, SP)                                                                     \
            { const int kt_ = wave + 4 * (s0 + (SP));                                    \
              const f16* hp_ = hq + (kt_ * 32 - 320);                                    \
              _Pragma("unroll")                                                          \
              for (int mt_ = 0; mt_ < 4; ++mt_) {                                        \
                  const unsigned long long* q_ =                                         \
                      (const unsigned long long*)(hp_ + (unsigned)(mt_ * 16 + l15) * 640u); \
                  pre[W][mt_ * 2]     = __hip_atomic_load(q_,     __ATOMIC_RELAXED,      \
                                                          __HIP_MEMORY_SCOPE_AGENT);     \
                  pre[W][mt_ * 2 + 1] = __hip_atomic_load(q_ + 1, __ATOMIC_RELAXED,      \
                                                          __HIP_MEMORY_SCOPE_AGENT);     \
              } }

            HLOAD(0, 0)
            HLOAD(1, 1)
            HLOAD(2, 2)
#pragma unroll
            for (int sp = 0; sp < 5; ++sp) {
#pragma unroll
                for (int mt = 0; mt < 4; ++mt) {
                    union { unsigned long long u[2]; half8 h; } xu;
                    xu.u[0] = pre[sp % 3][mt * 2];
                    xu.u[1] = pre[sp % 3][mt * 2 + 1];
                    half8 Ah = xu.h;
                    accH[mt][0] = __builtin_amdgcn_mfma_f32_16x16x32_f16(Ah, Bh[sp][0][0], accH[mt][0], 0, 0, 0);
                    accM[mt][0] = __builtin_amdgcn_mfma_f32_16x16x32_f16(Ah, Bh[sp][0][1], accM[mt][0], 0, 0, 0);
                    accH[mt][1] = __builtin_amdgcn_mfma_f32_16x16x32_f16(Ah, Bh[sp][1][0], accH[mt][1], 0, 0, 0);
                    accM[mt][1] = __builtin_amdgcn_mfma_f32_16x16x32_f16(Ah, Bh[sp][1][1], accM[mt][1], 0, 0, 0);
                }
                if (sp == 0) HLOAD(0, 3)
                if (sp == 1) HLOAD(1, 4)
            }
#undef HLOAD

            // ---- all-to-all K-merge through LDS ----
            __syncthreads();
#pragma unroll
            for (int mt = 0; mt < 4; ++mt)
#pragma unroll
                for (int nt = 0; nt < 2; ++nt)
                    obox[wave][mt][nt][lane] = accH[mt][nt] + accM[mt][nt] * (1.0f / 2048.0f);
            __syncthreads();
            f32x4 z0 = obox[0][wave][0][lane] + obox[1][wave][0][lane]
                     + obox[2][wave][0][lane] + obox[3][wave][0][lane];
            f32x4 z1 = obox[0][wave][1][lane] + obox[1][wave][1][lane]
                     + obox[2][wave][1][lane] + obox[3][wave][1][lane];
            z0 += f32x4{z0p[0], z0p[1], z0p[2], z0p[3]};
            z1 += f32x4{z1p[0], z1p[1], z1p[2], z1p[3]};

            // ---- epilogue: this wave owns batch rows wave*16 .. wave*16+15 ----
#pragma unroll
            for (int r = 0; r < 4; ++r) {
                float zi = z0[r], zg = z1[r];
                float zf = __shfl_xor(z0[r], 8, 64);  // f gate lives 8 lanes over
                float zo = __shfl_xor(z1[r], 8, 64);
                if (l15 < 8) {
                    float ig = 1.0f / (1.0f + __expf(-zi));
                    float fg = 1.0f / (1.0f + __expf(-zf));
                    float gg = tanhf(zg);
                    float og = 1.0f / (1.0f + __expf(-zo));
                    float c  = fg * cst[dd][r] + ig * gg;
                    cst[dd][r] = c;
                    float h = og * tanhf(c);
                    if (t < Lr[r]) sum[dd][r] += h;
                    hstage[wave * 16 + quad * 4 + r][l15] = (f16)h;
                }
            }
            __syncthreads();   // hstage complete
            if (tid < 128) {
                // 128 threads publish 128 x 8B write-through stores (bypass L1/L2)
                int rr = tid >> 1, hf = tid & 1;
                unsigned long long v = *(const unsigned long long*)&hstage[rr][hf * 4];
                __hip_atomic_store(
                    (unsigned long long*)(hnxt + (unsigned)rr * 640u + pc + hf * 4),
                    v, __ATOMIC_RELAXED, __HIP_MEMORY_SCOPE_AGENT);
            }
            __syncthreads();   // drains all waves' stores (vmcnt(0)) before the flag store
            if (tid == 0)
                __hip_atomic_store(myflags + p, (unsigned)(t + 1),
                                   __ATOMIC_RELAXED, __HIP_MEMORY_SCOPE_AGENT);

            // ---- pipelined burst: XZ for step t+G, this dir (overlaps flag propagation) ----
            int tf = t + G;
            if (tf < T) {
                int tx = tf;
                if (dd) tx = (tf < Lw) ? (Lw - 1 - tf) : tf;
                unsigned arow = ((unsigned)(wave * 16 + l15) * 512u + (unsigned)tx) * 320u + quad * 8;
                f32x4 aH[2], aM[2];
                aH[0] = f32x4{0.f, 0.f, 0.f, 0.f}; aM[0] = f32x4{0.f, 0.f, 0.f, 0.f};
                aH[1] = f32x4{0.f, 0.f, 0.f, 0.f}; aM[1] = f32x4{0.f, 0.f, 0.f, 0.f};
#pragma unroll
                for (int kt = 0; kt < 10; ++kt) {
                    const f16* bb = &Blds[dd][0][0][0] + kt * 512 + lane * 8;
                    half8 B00 = *(const half8*)(bb);
                    half8 B01 = *(const half8*)(bb + 5120);
                    half8 B10 = *(const half8*)(bb + 10240);
                    half8 B11 = *(const half8*)(bb + 15360);
                    half8 Ah = *(const half8*)(x16h + arow + kt * 32);
                    half8 Al = *(const half8*)(x16l + arow + kt * 32);
                    aH[0] = __builtin_amdgcn_mfma_f32_16x16x32_f16(Ah, B00, aH[0], 0, 0, 0);
                    aM[0] = __builtin_amdgcn_mfma_f32_16x16x32_f16(Ah, B10, aM[0], 0, 0, 0);
                    aM[0] = __builtin_amdgcn_mfma_f32_16x16x32_f16(Al, B00, aM[0], 0, 0, 0);
                    aH[1] = __builtin_amdgcn_mfma_f32_16x16x32_f16(Ah, B01, aH[1], 0, 0, 0);
                    aM[1] = __builtin_amdgcn_mfma_f32_16x16x32_f16(Ah, B11, aM[1], 0, 0, 0);
                    aM[1] = __builtin_amdgcn_mfma_f32_16x16x32_f16(Al, B01, aM[1], 0, 0, 0);
                }
                int slot = tf % RING;
#pragma unroll
                for (int r = 0; r < 4; ++r) {
                    unsigned rowi = (unsigned)(slot * 64 + wave * 16 + quad * 4 + r) * 32u;
                    mx[dd][rowi + l15]      = aH[0][r] + aM[0][r] * (1.0f / 2048.0f) + b0a[dd];
                    mx[dd][rowi + 16 + l15] = aH[1][r] + aM[1][r] * (1.0f / 2048.0f) + b1a[dd];
                }
            }
        }   // dir
    }   // t

#pragma unroll
    for (int dd = 0; dd < 2; ++dd)
        if (l15 < 8) {
#pragma unroll
            for (int r = 0; r < 4; ++r)
                out[(wave * 16 + quad * 4 + r) * 1200 + dd * 600 + pc + l15] =
                    sum[dd][r] * (1.0f / 512.0f);
        }
}

// ---------------- launcher ----------------
extern "C" void kernel_launch(void* const* d_in, const int* in_sizes, int n_in,
                              void* d_out, int out_size, void* d_ws, size_t ws_size,
                              hipStream_t stream) {
    const float* x   = (const float*)d_in[0];
    const int*   len = (const int*)  d_in[1];
    const float* Wf  = (const float*)d_in[3];
    const float* Uf  = (const float*)d_in[4];
    const float* bfv = (const float*)d_in[5];
    const float* Wb  = (const float*)d_in[6];
    const float* Ub  = (const float*)d_in[7];
    const float* bbv = (const float*)d_in[8];
    float* outp = (float*)d_out;

    char* w = (char*)d_ws;
    f16*      x16hp = (f16*)w;                         // 20,971,520 B
    f16*      x16lp = (f16*)(w + 20971520);            // 20,971,520 B
    f16*      bpkp  = (f16*)(w + 41943040);            // 18,432,000 B
    f16*      hbufp = (f16*)(w + 60375040);            //    327,680 B
    float*    xzp   = (float*)(w + 60702720);          // 150*13*64*32*4 = 15,974,400 B
    unsigned* flagp = (unsigned*)(w + 76677120);       //      1,024 B
    int*      maxtp = (int*)(w + 76678144);

    hipLaunchKernelGGL(lstm_prep, dim3(1024), dim3(256), 0, stream,
                       x, Wf, Uf, Wb, Ub, len,
                       x16hp, x16lp, bpkp, (unsigned*)hbufp, flagp, maxtp, outp);

    hipLaunchKernelGGL(lstm_main, dim3(GRID_MAIN), dim3(256), 0, stream,
                       x16hp, x16lp, bpkp, hbufp, xzp, flagp, maxtp, len, bfv, bbv, outp);
}

// Round 3
// 4703.255 us; speedup vs baseline: 2.0733x; 2.0733x over previous
//
#include <hip/hip_runtime.h>
#include <hip/hip_fp16.h>
#include <cmath>

typedef _Float16 f16;
typedef _Float16 half8 __attribute__((ext_vector_type(8)));
typedef float f32x4 __attribute__((ext_vector_type(4)));

#define P_WG   75          // workgroups per direction
#define GRID_MAIN (2*P_WG) // 150
#define G      12          // XZ lookahead distance
#define RING   13          // XZ ring slots (G+1)

#define X16_ELEMS  (64u*512u*320u)            // 10,485,760 f16 per plane
#define BPK_HALF   (2u*75u*2u*30u*64u*8u)     // 4,608,000 f16 (one term plane)
#define HBUF_F16   (2u*2u*64u*640u)           // dirs*bufs*rows*cols f16
#define HBUF_WORDS (HBUF_F16/2u)              // 81,920 u32
#define FLAG_WORDS 256u                       // 2 dirs x 128 u32 (75 flags + pads)

// ---------------- prep: rebuild all workspace state every launch ----------------
__global__ void lstm_prep(const float* __restrict__ x,
                          const float* __restrict__ Wf, const float* __restrict__ Uf,
                          const float* __restrict__ Wb, const float* __restrict__ Ub,
                          const int* __restrict__ len,
                          f16* __restrict__ x16h, f16* __restrict__ x16l,
                          f16* __restrict__ Bpk,
                          unsigned* __restrict__ hbw, unsigned* __restrict__ flags,
                          int* __restrict__ maxT, float* __restrict__ outp)
{
    const unsigned total = X16_ELEMS + BPK_HALF + HBUF_WORDS + FLAG_WORDS + 2u;
    for (unsigned e = blockIdx.x * blockDim.x + threadIdx.x; e < total;
         e += gridDim.x * blockDim.x) {
        if (e < X16_ELEMS) {
            unsigned k = e % 320u, r = e / 320u;   // r = b*512 + t
            float v = (k < 300u) ? x[r * 300u + k] : 0.0f;
            f16 hi = (f16)v;
            x16h[e] = hi;
            x16l[e] = (f16)((v - (float)hi) * 2048.0f);
        } else if (e < X16_ELEMS + BPK_HALF) {
            unsigned i = e - X16_ELEMS;
            // layout: [dir][p][term][nt][kt][lane][8]
            unsigned j    = i & 7u,  r1 = i >> 3;
            unsigned lane = r1 & 63u, r2 = r1 >> 6;
            unsigned kt   = r2 % 30u, r3 = r2 / 30u;
            unsigned nt   = r3 & 1u,  r4 = r3 >> 1;
            unsigned p    = r4 % 75u, dw = r4 / 75u;
            unsigned k = kt * 32u + (lane >> 4) * 8u + j;     // B[k][n], k-octet per quad
            unsigned n = nt * 16u + (lane & 15u);             // n = gate*8 + jj
            unsigned c = (n >> 3) * 600u + p * 8u + (n & 7u); // source column in [0,2400)
            float v = 0.0f;
            if (k < 300u)                    v = (dw ? Wb : Wf)[k * 2400u + c];
            else if (k >= 320u && k < 920u)  v = (dw ? Ub : Uf)[(k - 320u) * 2400u + c];
            f16 hi = (f16)v;
            unsigned base = (((((dw * 75u + p) * 2u + 0u) * 2u + nt) * 30u + kt) * 64u + lane) * 8u + j;
            Bpk[base]          = hi;
            Bpk[base + 30720u] = (f16)((v - (float)hi) * 2048.0f); // lo pre-scaled by 2^11
        } else if (e < X16_ELEMS + BPK_HALF + HBUF_WORDS) {
            hbw[e - X16_ELEMS - BPK_HALF] = 0u;   // zero h ping-pong buffers, both dirs
        } else if (e < X16_ELEMS + BPK_HALF + HBUF_WORDS + FLAG_WORDS) {
            unsigned q = e - (X16_ELEMS + BPK_HALF + HBUF_WORDS);
            unsigned q7 = q & 127u;
            flags[q] = (q7 < 75u) ? 0u : 0xFFFFFFFFu;   // pads always satisfied
        } else {
            unsigned q = e - (X16_ELEMS + BPK_HALF + HBUF_WORDS + FLAG_WORDS);
            if (q == 0u) {
                int m = 1;
                for (int b = 0; b < 64; ++b) { int L = len[b]; m = (L > m) ? L : m; }
                *maxT = m;
            } else {
                outp[0] = 1000.0f;   // sentinel: lstm_main always overwrites out[0]
            }
        }
    }
}

__device__ __forceinline__ float fsigm(float x) {
    return __builtin_amdgcn_rcpf(1.0f + __expf(-x));
}
__device__ __forceinline__ float ftanh(float x) {
    x = fminf(fmaxf(x, -15.0f), 15.0f);
    float e = __expf(2.0f * x);
    return (e - 1.0f) * __builtin_amdgcn_rcpf(e + 1.0f);
}

// ---------------- main persistent recurrent kernel ----------------
__global__ __launch_bounds__(256, 1)
void lstm_main(const f16* __restrict__ x16h, const f16* __restrict__ x16l,
               const f16* __restrict__ Bpk,
               f16* __restrict__ hbuf, float* __restrict__ xz,
               unsigned* flags, const int* __restrict__ maxT,
               const int* __restrict__ len,
               const float* __restrict__ bfv, const float* __restrict__ bbv,
               float* __restrict__ out)
{
    __shared__ f32x4 obox[4][4][2][64];   // 32 KB merge buffer
    __shared__ f16 hstage[64][8];         // 1 KB
    __shared__ f16 Bldsx[4][10][512];     // xz-part B (kt<10): 40 KB
    __shared__ f16 Bldsh[4][20][512];     // h-part B (kt 10..29): 80 KB

    const int tid  = threadIdx.x;
    const int wave = tid >> 6, lane = tid & 63;
    const int quad = lane >> 4, l15 = lane & 15;
    const int dir  = blockIdx.x & 1, p = blockIdx.x >> 1;
    const int pc   = p * 8;
    const int wg   = blockIdx.x;

    const int s0 = (wave < 2) ? 3 : 2;    // kt = wave + 4*(s0+sp), sp=0..4
    const unsigned bpk_base = (unsigned)(dir * 75 + p) * 4u * 30u * 512u;

    const float* bias = dir ? bbv : bfv;
    const float b0 = bias[((l15 >> 3)    ) * 600 + pc + (l15 & 7)];  // gates i|f tile
    const float b1 = bias[((l15 >> 3) + 2) * 600 + pc + (l15 & 7)];  // gates g|o tile

    int Lm[4], Lr[4];
#pragma unroll
    for (int mt = 0; mt < 4; ++mt) Lm[mt] = len[mt * 16 + l15];        // initial-burst A rows
    const int Lw = len[wave * 16 + l15];                               // steady-burst A rows
#pragma unroll
    for (int r = 0; r < 4; ++r)   Lr[r]  = len[wave * 16 + quad * 4 + r]; // epilogue rows

    f16* hb0 = hbuf + dir * (2 * 64 * 640);
    unsigned* myflags = flags + dir * 128;
    float* myxz = xz + (size_t)wg * (RING * 64 * 32);
    float cst[4] = {0, 0, 0, 0}, sum[4] = {0, 0, 0, 0};
    const int T = *maxT;

    // ---- stage B tiles into LDS: xz-part (kt<10) and h-part (kt 10..29) ----
    {
#pragma unroll
        for (int blk = 0; blk < 4; ++blk) {
            f16* blx = &Bldsx[blk][0][0];
            for (int i = tid; i < 640; i += 256)
                *(half8*)(blx + i * 8) =
                    *(const half8*)(Bpk + bpk_base + (unsigned)blk * 15360u + (unsigned)i * 8u);
            f16* blh = &Bldsh[blk][0][0];
            for (int i = tid; i < 1280; i += 256)
                *(half8*)(blh + i * 8) =
                    *(const half8*)(Bpk + bpk_base + (unsigned)blk * 15360u + 5120u + (unsigned)i * 8u);
        }
    }
    __syncthreads();

    // ---- initial burst: fill XZ ring slots 0..G-1 (wave g-split, full K) ----
#pragma unroll
    for (int jc = 0; jc < 3; ++jc) {
        int g = wave * 3 + jc;
        int tt = (g < 512) ? g : 511;
        unsigned arow[4];
#pragma unroll
        for (int mt = 0; mt < 4; ++mt) {
            int tx = tt;
            if (dir) tx = (tt < Lm[mt]) ? (Lm[mt] - 1 - tt) : tt;  // reverse_sequence
            arow[mt] = ((unsigned)(mt * 16 + l15) * 512u + (unsigned)tx) * 320u + quad * 8;
        }
        f32x4 aH[4][2], aM[4][2];
#pragma unroll
        for (int mt = 0; mt < 4; ++mt)
#pragma unroll
            for (int nt = 0; nt < 2; ++nt) {
                aH[mt][nt] = f32x4{0.f, 0.f, 0.f, 0.f};
                aM[mt][nt] = f32x4{0.f, 0.f, 0.f, 0.f};
            }
#pragma unroll
        for (int kt = 0; kt < 10; ++kt) {
            const f16* bb = &Bldsx[0][0][0] + kt * 512 + lane * 8;
            half8 B00 = *(const half8*)(bb);
            half8 B01 = *(const half8*)(bb + 5120);
            half8 B10 = *(const half8*)(bb + 10240);
            half8 B11 = *(const half8*)(bb + 15360);
#pragma unroll
            for (int mt = 0; mt < 4; ++mt) {
                half8 Ah = *(const half8*)(x16h + arow[mt] + kt * 32);
                half8 Al = *(const half8*)(x16l + arow[mt] + kt * 32);
                aH[mt][0] = __builtin_amdgcn_mfma_f32_16x16x32_f16(Ah, B00, aH[mt][0], 0, 0, 0);
                aM[mt][0] = __builtin_amdgcn_mfma_f32_16x16x32_f16(Ah, B10, aM[mt][0], 0, 0, 0);
                aM[mt][0] = __builtin_amdgcn_mfma_f32_16x16x32_f16(Al, B00, aM[mt][0], 0, 0, 0);
                aH[mt][1] = __builtin_amdgcn_mfma_f32_16x16x32_f16(Ah, B01, aH[mt][1], 0, 0, 0);
                aM[mt][1] = __builtin_amdgcn_mfma_f32_16x16x32_f16(Ah, B11, aM[mt][1], 0, 0, 0);
                aM[mt][1] = __builtin_amdgcn_mfma_f32_16x16x32_f16(Al, B01, aM[mt][1], 0, 0, 0);
            }
        }
#pragma unroll
        for (int mt = 0; mt < 4; ++mt)
#pragma unroll
            for (int r = 0; r < 4; ++r) {
                unsigned rowi = (unsigned)(g * 64 + mt * 16 + quad * 4 + r) * 32u;
                myxz[rowi + l15]      = aH[mt][0][r] + aM[mt][0][r] * (1.0f / 2048.0f) + b0;
                myxz[rowi + 16 + l15] = aH[mt][1][r] + aM[mt][1][r] * (1.0f / 2048.0f) + b1;
            }
    }
    __syncthreads();   // XZ slots 0..11 visible WG-wide (same CU: L1-coherent)

    for (int t = 0; t < T; ++t) {
        // ---- 1. early-issue x16 loads for burst step t+G (consumed after h-phase) ----
        int tf = t + G;
        int tq = (tf < T) ? tf : (T - 1);
        half8 axh[10], axl[10];
        {
            int tx = tq;
            if (dir) tx = (tq < Lw) ? (Lw - 1 - tq) : tq;
            unsigned arow = ((unsigned)(wave * 16 + l15) * 512u + (unsigned)tx) * 320u + quad * 8;
#pragma unroll
            for (int kt = 0; kt < 10; ++kt) {
                axh[kt] = *(const half8*)(x16h + arow + kt * 32);
                axl[kt] = *(const half8*)(x16l + arow + kt * 32);
            }
        }
        __builtin_amdgcn_sched_barrier(0);   // pin load issue before the wait

        // ---- 2. preload this step's XZ into registers (WG-local, L1-warm) ----
        float z0p[4], z1p[4];
        {
            int slot = t % RING;
            unsigned rbase = (unsigned)(slot * 64 + wave * 16 + quad * 4) * 32u;
#pragma unroll
            for (int r = 0; r < 4; ++r) {
                z0p[r] = myxz[rbase + r * 32 + l15];
                z1p[r] = myxz[rbase + r * 32 + 16 + l15];
            }
        }

        const f16* hcur = hb0 + (t & 1) * (64 * 640);
        f16*       hnxt = hb0 + ((t + 1) & 1) * (64 * 640);

        // ---- 3. wait: wave 0 busy-polls all 75 producer flags, barrier releases WG ----
        if (t > 0) {
            const unsigned tgt = (unsigned)t;
            if (wave == 0) {
                const unsigned long long* f8 = (const unsigned long long*)myflags;
                for (;;) {
                    unsigned long long v = ~0ull;
                    if (lane < 38)
                        v = __hip_atomic_load(&f8[lane], __ATOMIC_RELAXED, __HIP_MEMORY_SCOPE_AGENT);
                    bool bad = ((unsigned)v < tgt) || ((unsigned)(v >> 32) < tgt);
                    if (!__any(bad)) break;
                }
            }
            __syncthreads();
        }

        // ---- 4. h-part: batch MALL loads (3-deep window); B frags from LDS ----
        f32x4 accH[4][2], accM[4][2];
#pragma unroll
        for (int mt = 0; mt < 4; ++mt)
#pragma unroll
            for (int nt = 0; nt < 2; ++nt) {
                accH[mt][nt] = f32x4{0.f, 0.f, 0.f, 0.f};
                accM[mt][nt] = f32x4{0.f, 0.f, 0.f, 0.f};
            }

        unsigned long long pre[3][8];     // [window][mt*2+half] : 48 VGPRs
        const f16* hq = hcur + quad * 8;
#define HLOAD(W, SP)                                                                     \
        { const int kt_ = wave + 4 * (s0 + (SP));                                        \
          const f16* hp_ = hq + (kt_ * 32 - 320);                                        \
          _Pragma("unroll")                                                              \
          for (int mt_ = 0; mt_ < 4; ++mt_) {                                            \
              const unsigned long long* q_ =                                             \
                  (const unsigned long long*)(hp_ + (unsigned)(mt_ * 16 + l15) * 640u);  \
              pre[W][mt_ * 2]     = __hip_atomic_load(q_,     __ATOMIC_RELAXED,          \
                                                      __HIP_MEMORY_SCOPE_AGENT);         \
              pre[W][mt_ * 2 + 1] = __hip_atomic_load(q_ + 1, __ATOMIC_RELAXED,          \
                                                      __HIP_MEMORY_SCOPE_AGENT);         \
          } }

        HLOAD(0, 0)
        HLOAD(1, 1)
        HLOAD(2, 2)
#pragma unroll
        for (int sp = 0; sp < 5; ++sp) {
            const int kt = wave + 4 * (s0 + sp);
            const f16* bh = &Bldsh[0][0][0] + (kt - 10) * 512 + lane * 8;
            half8 Bc00 = *(const half8*)(bh);             // tm0 nt0
            half8 Bc01 = *(const half8*)(bh + 10240);     // tm0 nt1
            half8 Bc10 = *(const half8*)(bh + 20480);     // tm1 nt0
            half8 Bc11 = *(const half8*)(bh + 30720);     // tm1 nt1
#pragma unroll
            for (int mt = 0; mt < 4; ++mt) {
                union { unsigned long long u[2]; half8 h; } xu;
                xu.u[0] = pre[sp % 3][mt * 2];
                xu.u[1] = pre[sp % 3][mt * 2 + 1];
                half8 Ah = xu.h;
                accH[mt][0] = __builtin_amdgcn_mfma_f32_16x16x32_f16(Ah, Bc00, accH[mt][0], 0, 0, 0);
                accM[mt][0] = __builtin_amdgcn_mfma_f32_16x16x32_f16(Ah, Bc10, accM[mt][0], 0, 0, 0);
                accH[mt][1] = __builtin_amdgcn_mfma_f32_16x16x32_f16(Ah, Bc01, accH[mt][1], 0, 0, 0);
                accM[mt][1] = __builtin_amdgcn_mfma_f32_16x16x32_f16(Ah, Bc11, accM[mt][1], 0, 0, 0);
            }
            if (sp == 0) HLOAD(0, 3)
            if (sp == 1) HLOAD(1, 4)
        }
#undef HLOAD

        // ---- 5. burst MFMAs for t+G (x16 data arrived long ago), store ring ----
        {
            f32x4 aH[2], aM[2];
            aH[0] = f32x4{0.f, 0.f, 0.f, 0.f}; aM[0] = f32x4{0.f, 0.f, 0.f, 0.f};
            aH[1] = f32x4{0.f, 0.f, 0.f, 0.f}; aM[1] = f32x4{0.f, 0.f, 0.f, 0.f};
#pragma unroll
            for (int kt = 0; kt < 10; ++kt) {
                const f16* bb = &Bldsx[0][0][0] + kt * 512 + lane * 8;
                half8 B00 = *(const half8*)(bb);
                half8 B01 = *(const half8*)(bb + 5120);
                half8 B10 = *(const half8*)(bb + 10240);
                half8 B11 = *(const half8*)(bb + 15360);
                aH[0] = __builtin_amdgcn_mfma_f32_16x16x32_f16(axh[kt], B00, aH[0], 0, 0, 0);
                aM[0] = __builtin_amdgcn_mfma_f32_16x16x32_f16(axh[kt], B10, aM[0], 0, 0, 0);
                aM[0] = __builtin_amdgcn_mfma_f32_16x16x32_f16(axl[kt], B00, aM[0], 0, 0, 0);
                aH[1] = __builtin_amdgcn_mfma_f32_16x16x32_f16(axh[kt], B01, aH[1], 0, 0, 0);
                aM[1] = __builtin_amdgcn_mfma_f32_16x16x32_f16(axh[kt], B11, aM[1], 0, 0, 0);
                aM[1] = __builtin_amdgcn_mfma_f32_16x16x32_f16(axl[kt], B01, aM[1], 0, 0, 0);
            }
            if (tf < T) {
                int slot = tf % RING;
#pragma unroll
                for (int r = 0; r < 4; ++r) {
                    unsigned rowi = (unsigned)(slot * 64 + wave * 16 + quad * 4 + r) * 32u;
                    myxz[rowi + l15]      = aH[0][r] + aM[0][r] * (1.0f / 2048.0f) + b0;
                    myxz[rowi + 16 + l15] = aH[1][r] + aM[1][r] * (1.0f / 2048.0f) + b1;
                }
            }
        }

        // ---- 6. all-to-all K-merge through LDS ----
        __syncthreads();
#pragma unroll
        for (int mt = 0; mt < 4; ++mt)
#pragma unroll
            for (int nt = 0; nt < 2; ++nt)
                obox[wave][mt][nt][lane] = accH[mt][nt] + accM[mt][nt] * (1.0f / 2048.0f);
        __syncthreads();
        f32x4 z0 = obox[0][wave][0][lane] + obox[1][wave][0][lane]
                 + obox[2][wave][0][lane] + obox[3][wave][0][lane];
        f32x4 z1 = obox[0][wave][1][lane] + obox[1][wave][1][lane]
                 + obox[2][wave][1][lane] + obox[3][wave][1][lane];
        z0 += f32x4{z0p[0], z0p[1], z0p[2], z0p[3]};
        z1 += f32x4{z1p[0], z1p[1], z1p[2], z1p[3]};

        // ---- epilogue: this wave owns batch rows wave*16 .. wave*16+15 ----
#pragma unroll
        for (int r = 0; r < 4; ++r) {
            float zi = z0[r], zg = z1[r];
            float zf = __shfl_xor(z0[r], 8, 64);  // f gate lives 8 lanes over
            float zo = __shfl_xor(z1[r], 8, 64);
            if (l15 < 8) {
                float ig = fsigm(zi);
                float fg = fsigm(zf);
                float gg = ftanh(zg);
                float og = fsigm(zo);
                float c  = fg * cst[r] + ig * gg;
                cst[r] = c;
                float h = og * ftanh(c);
                if (t < Lr[r]) sum[r] += h;
                hstage[wave * 16 + quad * 4 + r][l15] = (f16)h;
            }
        }
        __syncthreads();   // hstage complete
        if (tid < 128) {
            // 128 threads publish 128 x 8B write-through stores (bypass L1/L2)
            int rr = tid >> 1, hf = tid & 1;
            unsigned long long v = *(const unsigned long long*)&hstage[rr][hf * 4];
            __hip_atomic_store(
                (unsigned long long*)(hnxt + (unsigned)rr * 640u + pc + hf * 4),
                v, __ATOMIC_RELAXED, __HIP_MEMORY_SCOPE_AGENT);
        }
        __syncthreads();   // drains all waves' stores (vmcnt(0)) before the flag store
        if (tid == 0)
            __hip_atomic_store(myflags + p, (unsigned)(t + 1),
                               __ATOMIC_RELAXED, __HIP_MEMORY_SCOPE_AGENT);
    }

    if (l15 < 8) {
#pragma unroll
        for (int r = 0; r < 4; ++r)
            out[(wave * 16 + quad * 4 + r) * 1200 + dir * 600 + pc + l15] =
                sum[r] * (1.0f / 512.0f);
    }
}

// ---------------- launcher ----------------
extern "C" void kernel_launch(void* const* d_in, const int* in_sizes, int n_in,
                              void* d_out, int out_size, void* d_ws, size_t ws_size,
                              hipStream_t stream) {
    const float* x   = (const float*)d_in[0];
    const int*   len = (const int*)  d_in[1];
    const float* Wf  = (const float*)d_in[3];
    const float* Uf  = (const float*)d_in[4];
    const float* bfv = (const float*)d_in[5];
    const float* Wb  = (const float*)d_in[6];
    const float* Ub  = (const float*)d_in[7];
    const float* bbv = (const float*)d_in[8];
    float* outp = (float*)d_out;

    char* w = (char*)d_ws;
    f16*      x16hp = (f16*)w;                         // 20,971,520 B
    f16*      x16lp = (f16*)(w + 20971520);            // 20,971,520 B
    f16*      bpkp  = (f16*)(w + 41943040);            // 18,432,000 B
    f16*      hbufp = (f16*)(w + 60375040);            //    327,680 B
    float*    xzp   = (float*)(w + 60702720);          // 150*13*64*32*4 = 15,974,400 B
    unsigned* flagp = (unsigned*)(w + 76677120);       //      1,024 B
    int*      maxtp = (int*)(w + 76678144);

    hipLaunchKernelGGL(lstm_prep, dim3(1024), dim3(256), 0, stream,
                       x, Wf, Uf, Wb, Ub, len,
                       x16hp, x16lp, bpkp, (unsigned*)hbufp, flagp, maxtp, outp);

    hipLaunchKernelGGL(lstm_main, dim3(GRID_MAIN), dim3(256), 0, stream,
                       x16hp, x16lp, bpkp, hbufp, xzp, flagp, maxtp, len, bfv, bbv, outp);
}

// Round 4
// 4541.840 us; speedup vs baseline: 2.1470x; 1.0355x over previous
//
#include <hip/hip_runtime.h>
#include <hip/hip_fp16.h>
#include <cmath>

typedef _Float16 f16;
typedef _Float16 half8 __attribute__((ext_vector_type(8)));
typedef float f32x4 __attribute__((ext_vector_type(4)));

#define P_WG   75          // workgroups per direction
#define GRID_MAIN (2*P_WG) // 150
#define G      12          // XZ lookahead distance
#define RING   13          // XZ ring slots (G+1)

#define X16_ELEMS  (64u*512u*320u)            // 10,485,760 f16 per plane
#define BPK_HALF   (2u*75u*2u*30u*64u*8u)     // 4,608,000 f16 (one term plane)
#define HBUF_F16   (2u*2u*64u*640u)           // dirs*bufs*rows*cols f16
#define HBUF_WORDS (HBUF_F16/2u)              // 81,920 u32
#define FLAG_WORDS 256u                       // 2 dirs x 128 u32 (75 flags + pads)

// ---------------- prep: rebuild all workspace state every launch ----------------
__global__ void lstm_prep(const float* __restrict__ x,
                          const float* __restrict__ Wf, const float* __restrict__ Uf,
                          const float* __restrict__ Wb, const float* __restrict__ Ub,
                          const int* __restrict__ len,
                          f16* __restrict__ x16h, f16* __restrict__ x16l,
                          f16* __restrict__ Bpk,
                          unsigned* __restrict__ hbw, unsigned* __restrict__ flags,
                          int* __restrict__ maxT, float* __restrict__ outp)
{
    const unsigned total = X16_ELEMS + BPK_HALF + HBUF_WORDS + FLAG_WORDS + 2u;
    for (unsigned e = blockIdx.x * blockDim.x + threadIdx.x; e < total;
         e += gridDim.x * blockDim.x) {
        if (e < X16_ELEMS) {
            unsigned k = e % 320u, r = e / 320u;   // r = b*512 + t
            float v = (k < 300u) ? x[r * 300u + k] : 0.0f;
            f16 hi = (f16)v;
            x16h[e] = hi;
            x16l[e] = (f16)((v - (float)hi) * 2048.0f);
        } else if (e < X16_ELEMS + BPK_HALF) {
            unsigned i = e - X16_ELEMS;
            // layout: [dir][p][term][nt][kt][lane][8]
            unsigned j    = i & 7u,  r1 = i >> 3;
            unsigned lane = r1 & 63u, r2 = r1 >> 6;
            unsigned kt   = r2 % 30u, r3 = r2 / 30u;
            unsigned nt   = r3 & 1u,  r4 = r3 >> 1;
            unsigned p    = r4 % 75u, dw = r4 / 75u;
            unsigned k = kt * 32u + (lane >> 4) * 8u + j;     // B[k][n], k-octet per quad
            unsigned n = nt * 16u + (lane & 15u);             // n = gate*8 + jj
            unsigned c = (n >> 3) * 600u + p * 8u + (n & 7u); // source column in [0,2400)
            float v = 0.0f;
            if (k < 300u)                    v = (dw ? Wb : Wf)[k * 2400u + c];
            else if (k >= 320u && k < 920u)  v = (dw ? Ub : Uf)[(k - 320u) * 2400u + c];
            f16 hi = (f16)v;
            unsigned base = (((((dw * 75u + p) * 2u + 0u) * 2u + nt) * 30u + kt) * 64u + lane) * 8u + j;
            Bpk[base]          = hi;
            Bpk[base + 30720u] = (f16)((v - (float)hi) * 2048.0f); // lo pre-scaled by 2^11
        } else if (e < X16_ELEMS + BPK_HALF + HBUF_WORDS) {
            hbw[e - X16_ELEMS - BPK_HALF] = 0u;   // zero h ping-pong buffers, both dirs
        } else if (e < X16_ELEMS + BPK_HALF + HBUF_WORDS + FLAG_WORDS) {
            unsigned q = e - (X16_ELEMS + BPK_HALF + HBUF_WORDS);
            unsigned q7 = q & 127u;
            flags[q] = (q7 < 75u) ? 0u : 0xFFFFFFFFu;   // pads always satisfied
        } else {
            unsigned q = e - (X16_ELEMS + BPK_HALF + HBUF_WORDS + FLAG_WORDS);
            if (q == 0u) {
                int m = 1;
                for (int b = 0; b < 64; ++b) { int L = len[b]; m = (L > m) ? L : m; }
                *maxT = m;
            } else {
                outp[0] = 1000.0f;   // sentinel: lstm_main always overwrites out[0]
            }
        }
    }
}

__device__ __forceinline__ float fsigm(float x) {
    return __builtin_amdgcn_rcpf(1.0f + __expf(-x));
}
__device__ __forceinline__ float ftanh(float x) {
    x = fminf(fmaxf(x, -15.0f), 15.0f);
    float e = __expf(2.0f * x);
    return (e - 1.0f) * __builtin_amdgcn_rcpf(e + 1.0f);
}

// ---------------- main persistent recurrent kernel ----------------
__global__ __launch_bounds__(256, 1)
void lstm_main(const f16* __restrict__ x16h, const f16* __restrict__ x16l,
               const f16* __restrict__ Bpk,
               f16* __restrict__ hbuf, float* __restrict__ xz,
               unsigned* flags, const int* __restrict__ maxT,
               const int* __restrict__ len,
               const float* __restrict__ bfv, const float* __restrict__ bbv,
               float* __restrict__ out)
{
    __shared__ f32x4 obox[4][4][2][64];   // 32 KB merge buffer
    __shared__ f16 hstage[64][8];         // 1 KB
    __shared__ f16 Bldsx[4][10][512];     // xz-part B (kt<10): 40 KB
    __shared__ f16 Bldsh[4][20][512];     // h-part B (kt 10..29): 80 KB

    const int tid  = threadIdx.x;
    const int wave = tid >> 6, lane = tid & 63;
    const int quad = lane >> 4, l15 = lane & 15;
    const int dir  = blockIdx.x & 1, p = blockIdx.x >> 1;
    const int pc   = p * 8;
    const int wg   = blockIdx.x;

    const int s0 = (wave < 2) ? 3 : 2;    // kt = wave + 4*(s0+sp), sp=0..4
    const unsigned bpk_base = (unsigned)(dir * 75 + p) * 4u * 30u * 512u;

    const float* bias = dir ? bbv : bfv;
    const float b0 = bias[((l15 >> 3)    ) * 600 + pc + (l15 & 7)];  // gates i|f tile
    const float b1 = bias[((l15 >> 3) + 2) * 600 + pc + (l15 & 7)];  // gates g|o tile

    int Lm[4], Lr[4];
#pragma unroll
    for (int mt = 0; mt < 4; ++mt) Lm[mt] = len[mt * 16 + l15];        // initial-burst A rows
    const int Lw = len[wave * 16 + l15];                               // steady-burst A rows
#pragma unroll
    for (int r = 0; r < 4; ++r)   Lr[r]  = len[wave * 16 + quad * 4 + r]; // epilogue rows

    f16* hb0 = hbuf + dir * (2 * 64 * 640);
    unsigned* myflags = flags + dir * 128;
    float* myxz = xz + (size_t)wg * (RING * 64 * 32);
    float cst[4] = {0, 0, 0, 0}, sum[4] = {0, 0, 0, 0};
    const int T = *maxT;

    // ---- stage B tiles into LDS: xz-part (kt<10) and h-part (kt 10..29) ----
    {
#pragma unroll
        for (int blk = 0; blk < 4; ++blk) {
            f16* blx = &Bldsx[blk][0][0];
            for (int i = tid; i < 640; i += 256)
                *(half8*)(blx + i * 8) =
                    *(const half8*)(Bpk + bpk_base + (unsigned)blk * 15360u + (unsigned)i * 8u);
            f16* blh = &Bldsh[blk][0][0];
            for (int i = tid; i < 1280; i += 256)
                *(half8*)(blh + i * 8) =
                    *(const half8*)(Bpk + bpk_base + (unsigned)blk * 15360u + 5120u + (unsigned)i * 8u);
        }
    }
    __syncthreads();

    // ---- initial burst: fill XZ ring slots 0..G-1 (wave g-split, full K) ----
#pragma unroll
    for (int jc = 0; jc < 3; ++jc) {
        int g = wave * 3 + jc;
        int tt = (g < 512) ? g : 511;
        unsigned arow[4];
#pragma unroll
        for (int mt = 0; mt < 4; ++mt) {
            int tx = tt;
            if (dir) tx = (tt < Lm[mt]) ? (Lm[mt] - 1 - tt) : tt;  // reverse_sequence
            arow[mt] = ((unsigned)(mt * 16 + l15) * 512u + (unsigned)tx) * 320u + quad * 8;
        }
        f32x4 aH[4][2], aM[4][2];
#pragma unroll
        for (int mt = 0; mt < 4; ++mt)
#pragma unroll
            for (int nt = 0; nt < 2; ++nt) {
                aH[mt][nt] = f32x4{0.f, 0.f, 0.f, 0.f};
                aM[mt][nt] = f32x4{0.f, 0.f, 0.f, 0.f};
            }
#pragma unroll
        for (int kt = 0; kt < 10; ++kt) {
            const f16* bb = &Bldsx[0][0][0] + kt * 512 + lane * 8;
            half8 B00 = *(const half8*)(bb);
            half8 B01 = *(const half8*)(bb + 5120);
            half8 B10 = *(const half8*)(bb + 10240);
            half8 B11 = *(const half8*)(bb + 15360);
#pragma unroll
            for (int mt = 0; mt < 4; ++mt) {
                half8 Ah = *(const half8*)(x16h + arow[mt] + kt * 32);
                half8 Al = *(const half8*)(x16l + arow[mt] + kt * 32);
                aH[mt][0] = __builtin_amdgcn_mfma_f32_16x16x32_f16(Ah, B00, aH[mt][0], 0, 0, 0);
                aM[mt][0] = __builtin_amdgcn_mfma_f32_16x16x32_f16(Ah, B10, aM[mt][0], 0, 0, 0);
                aM[mt][0] = __builtin_amdgcn_mfma_f32_16x16x32_f16(Al, B00, aM[mt][0], 0, 0, 0);
                aH[mt][1] = __builtin_amdgcn_mfma_f32_16x16x32_f16(Ah, B01, aH[mt][1], 0, 0, 0);
                aM[mt][1] = __builtin_amdgcn_mfma_f32_16x16x32_f16(Ah, B11, aM[mt][1], 0, 0, 0);
                aM[mt][1] = __builtin_amdgcn_mfma_f32_16x16x32_f16(Al, B01, aM[mt][1], 0, 0, 0);
            }
        }
#pragma unroll
        for (int mt = 0; mt < 4; ++mt)
#pragma unroll
            for (int r = 0; r < 4; ++r) {
                unsigned rowi = (unsigned)(g * 64 + mt * 16 + quad * 4 + r) * 32u;
                myxz[rowi + l15]      = aH[mt][0][r] + aM[mt][0][r] * (1.0f / 2048.0f) + b0;
                myxz[rowi + 16 + l15] = aH[mt][1][r] + aM[mt][1][r] * (1.0f / 2048.0f) + b1;
            }
    }
    __syncthreads();   // XZ slots 0..11 visible WG-wide (same CU: L1-coherent)

    for (int t = 0; t < T; ++t) {
        // ---- 1. full xz burst for step t+G, BEFORE the wait (absorbed by flag-prop
        //         window; no dependence on h(t)) ----
        int tf = t + G;
        int tq = (tf < T) ? tf : (T - 1);
        {
            int tx = tq;
            if (dir) tx = (tq < Lw) ? (Lw - 1 - tq) : tq;
            unsigned arow = ((unsigned)(wave * 16 + l15) * 512u + (unsigned)tx) * 320u + quad * 8;
            half8 axh[10], axl[10];
#pragma unroll
            for (int kt = 0; kt < 10; ++kt) {
                axh[kt] = *(const half8*)(x16h + arow + kt * 32);
                axl[kt] = *(const half8*)(x16l + arow + kt * 32);
            }
            f32x4 aH[2], aM[2];
            aH[0] = f32x4{0.f, 0.f, 0.f, 0.f}; aM[0] = f32x4{0.f, 0.f, 0.f, 0.f};
            aH[1] = f32x4{0.f, 0.f, 0.f, 0.f}; aM[1] = f32x4{0.f, 0.f, 0.f, 0.f};
#pragma unroll
            for (int kt = 0; kt < 10; ++kt) {
                const f16* bb = &Bldsx[0][0][0] + kt * 512 + lane * 8;
                half8 B00 = *(const half8*)(bb);
                half8 B01 = *(const half8*)(bb + 5120);
                half8 B10 = *(const half8*)(bb + 10240);
                half8 B11 = *(const half8*)(bb + 15360);
                aH[0] = __builtin_amdgcn_mfma_f32_16x16x32_f16(axh[kt], B00, aH[0], 0, 0, 0);
                aM[0] = __builtin_amdgcn_mfma_f32_16x16x32_f16(axh[kt], B10, aM[0], 0, 0, 0);
                aM[0] = __builtin_amdgcn_mfma_f32_16x16x32_f16(axl[kt], B00, aM[0], 0, 0, 0);
                aH[1] = __builtin_amdgcn_mfma_f32_16x16x32_f16(axh[kt], B01, aH[1], 0, 0, 0);
                aM[1] = __builtin_amdgcn_mfma_f32_16x16x32_f16(axh[kt], B11, aM[1], 0, 0, 0);
                aM[1] = __builtin_amdgcn_mfma_f32_16x16x32_f16(axl[kt], B01, aM[1], 0, 0, 0);
            }
            if (tf < T) {
                int slot = tf % RING;
#pragma unroll
                for (int r = 0; r < 4; ++r) {
                    unsigned rowi = (unsigned)(slot * 64 + wave * 16 + quad * 4 + r) * 32u;
                    myxz[rowi + l15]      = aH[0][r] + aM[0][r] * (1.0f / 2048.0f) + b0;
                    myxz[rowi + 16 + l15] = aH[1][r] + aM[1][r] * (1.0f / 2048.0f) + b1;
                }
            }
        }

        // ---- 2. preload this step's XZ into registers (same-wave rows: L1-local) ----
        float z0p[4], z1p[4];
        {
            int slot = t % RING;
            unsigned rbase = (unsigned)(slot * 64 + wave * 16 + quad * 4) * 32u;
#pragma unroll
            for (int r = 0; r < 4; ++r) {
                z0p[r] = myxz[rbase + r * 32 + l15];
                z1p[r] = myxz[rbase + r * 32 + 16 + l15];
            }
        }

        const f16* hcur = hb0 + (t & 1) * (64 * 640);
        f16*       hnxt = hb0 + ((t + 1) & 1) * (64 * 640);

        // ---- 3. wait: EVERY wave busy-polls all 75 producer flags (no barrier —
        //         each wave issues its h loads the moment it sees the flags) ----
        if (t > 0) {
            const unsigned tgt = (unsigned)t;
            const unsigned long long* f8 = (const unsigned long long*)myflags;
            for (;;) {
                unsigned long long v = ~0ull;
                if (lane < 38)
                    v = __hip_atomic_load(&f8[lane], __ATOMIC_RELAXED, __HIP_MEMORY_SCOPE_AGENT);
                bool bad = ((unsigned)v < tgt) || ((unsigned)(v >> 32) < tgt);
                if (!__any(bad)) break;
            }
        }

        // ---- 4. h-part: issue ALL 40 MALL loads in one batch (1 RT), then MFMAs ----
        f32x4 accH[4][2], accM[4][2];
#pragma unroll
        for (int mt = 0; mt < 4; ++mt)
#pragma unroll
            for (int nt = 0; nt < 2; ++nt) {
                accH[mt][nt] = f32x4{0.f, 0.f, 0.f, 0.f};
                accM[mt][nt] = f32x4{0.f, 0.f, 0.f, 0.f};
            }

        unsigned long long pre[5][8];     // [sp][mt*2+half] : 80 VGPRs
        const f16* hq = hcur + quad * 8;
#define HLOAD(SP)                                                                        \
        { const int kt_ = wave + 4 * (s0 + (SP));                                        \
          const f16* hp_ = hq + (kt_ * 32 - 320);                                        \
          _Pragma("unroll")                                                              \
          for (int mt_ = 0; mt_ < 4; ++mt_) {                                            \
              const unsigned long long* q_ =                                             \
                  (const unsigned long long*)(hp_ + (unsigned)(mt_ * 16 + l15) * 640u);  \
              pre[SP][mt_ * 2]     = __hip_atomic_load(q_,     __ATOMIC_RELAXED,         \
                                                       __HIP_MEMORY_SCOPE_AGENT);        \
              pre[SP][mt_ * 2 + 1] = __hip_atomic_load(q_ + 1, __ATOMIC_RELAXED,         \
                                                       __HIP_MEMORY_SCOPE_AGENT);        \
          } }

        HLOAD(0) HLOAD(1) HLOAD(2) HLOAD(3) HLOAD(4)
#undef HLOAD
#pragma unroll
        for (int sp = 0; sp < 5; ++sp) {
            const int kt = wave + 4 * (s0 + sp);
            const f16* bh = &Bldsh[0][0][0] + (kt - 10) * 512 + lane * 8;
            half8 Bc00 = *(const half8*)(bh);             // tm0 nt0
            half8 Bc01 = *(const half8*)(bh + 10240);     // tm0 nt1
            half8 Bc10 = *(const half8*)(bh + 20480);     // tm1 nt0
            half8 Bc11 = *(const half8*)(bh + 30720);     // tm1 nt1
#pragma unroll
            for (int mt = 0; mt < 4; ++mt) {
                union { unsigned long long u[2]; half8 h; } xu;
                xu.u[0] = pre[sp][mt * 2];
                xu.u[1] = pre[sp][mt * 2 + 1];
                half8 Ah = xu.h;
                accH[mt][0] = __builtin_amdgcn_mfma_f32_16x16x32_f16(Ah, Bc00, accH[mt][0], 0, 0, 0);
                accM[mt][0] = __builtin_amdgcn_mfma_f32_16x16x32_f16(Ah, Bc10, accM[mt][0], 0, 0, 0);
                accH[mt][1] = __builtin_amdgcn_mfma_f32_16x16x32_f16(Ah, Bc01, accH[mt][1], 0, 0, 0);
                accM[mt][1] = __builtin_amdgcn_mfma_f32_16x16x32_f16(Ah, Bc11, accM[mt][1], 0, 0, 0);
            }
        }

        // ---- 5. all-to-all K-merge through LDS ----
        __syncthreads();
#pragma unroll
        for (int mt = 0; mt < 4; ++mt)
#pragma unroll
            for (int nt = 0; nt < 2; ++nt)
                obox[wave][mt][nt][lane] = accH[mt][nt] + accM[mt][nt] * (1.0f / 2048.0f);
        __syncthreads();
        f32x4 z0 = obox[0][wave][0][lane] + obox[1][wave][0][lane]
                 + obox[2][wave][0][lane] + obox[3][wave][0][lane];
        f32x4 z1 = obox[0][wave][1][lane] + obox[1][wave][1][lane]
                 + obox[2][wave][1][lane] + obox[3][wave][1][lane];
        z0 += f32x4{z0p[0], z0p[1], z0p[2], z0p[3]};
        z1 += f32x4{z1p[0], z1p[1], z1p[2], z1p[3]};

        // ---- 6. epilogue: this wave owns batch rows wave*16 .. wave*16+15 ----
#pragma unroll
        for (int r = 0; r < 4; ++r) {
            float zi = z0[r], zg = z1[r];
            float zf = __shfl_xor(z0[r], 8, 64);  // f gate lives 8 lanes over
            float zo = __shfl_xor(z1[r], 8, 64);
            if (l15 < 8) {
                float ig = fsigm(zi);
                float fg = fsigm(zf);
                float gg = ftanh(zg);
                float og = fsigm(zo);
                float c  = fg * cst[r] + ig * gg;
                cst[r] = c;
                float h = og * ftanh(c);
                if (t < Lr[r]) sum[r] += h;
                hstage[wave * 16 + quad * 4 + r][l15] = (f16)h;
            }
        }
        __syncthreads();   // hstage complete
        if (tid < 128) {
            // 128 threads publish 128 x 8B write-through stores (bypass L1/L2)
            int rr = tid >> 1, hf = tid & 1;
            unsigned long long v = *(const unsigned long long*)&hstage[rr][hf * 4];
            __hip_atomic_store(
                (unsigned long long*)(hnxt + (unsigned)rr * 640u + pc + hf * 4),
                v, __ATOMIC_RELAXED, __HIP_MEMORY_SCOPE_AGENT);
        }
        __syncthreads();   // drains all waves' stores (vmcnt(0)) before the flag store
        if (tid == 0)
            __hip_atomic_store(myflags + p, (unsigned)(t + 1),
                               __ATOMIC_RELAXED, __HIP_MEMORY_SCOPE_AGENT);
    }

    if (l15 < 8) {
#pragma unroll
        for (int r = 0; r < 4; ++r)
            out[(wave * 16 + quad * 4 + r) * 1200 + dir * 600 + pc + l15] =
                sum[r] * (1.0f / 512.0f);
    }
}

// ---------------- launcher ----------------
extern "C" void kernel_launch(void* const* d_in, const int* in_sizes, int n_in,
                              void* d_out, int out_size, void* d_ws, size_t ws_size,
                              hipStream_t stream) {
    const float* x   = (const float*)d_in[0];
    const int*   len = (const int*)  d_in[1];
    const float* Wf  = (const float*)d_in[3];
    const float* Uf  = (const float*)d_in[4];
    const float* bfv = (const float*)d_in[5];
    const float* Wb  = (const float*)d_in[6];
    const float* Ub  = (const float*)d_in[7];
    const float* bbv = (const float*)d_in[8];
    float* outp = (float*)d_out;

    char* w = (char*)d_ws;
    f16*      x16hp = (f16*)w;                         // 20,971,520 B
    f16*      x16lp = (f16*)(w + 20971520);            // 20,971,520 B
    f16*      bpkp  = (f16*)(w + 41943040);            // 18,432,000 B
    f16*      hbufp = (f16*)(w + 60375040);            //    327,680 B
    float*    xzp   = (float*)(w + 60702720);          // 150*13*64*32*4 = 15,974,400 B
    unsigned* flagp = (unsigned*)(w + 76677120);       //      1,024 B
    int*      maxtp = (int*)(w + 76678144);

    hipLaunchKernelGGL(lstm_prep, dim3(1024), dim3(256), 0, stream,
                       x, Wf, Uf, Wb, Ub, len,
                       x16hp, x16lp, bpkp, (unsigned*)hbufp, flagp, maxtp, outp);

    hipLaunchKernelGGL(lstm_main, dim3(GRID_MAIN), dim3(256), 0, stream,
                       x16hp, x16lp, bpkp, hbufp, xzp, flagp, maxtp, len, bfv, bbv, outp);
}